// Round 3
// baseline (2060.364 us; speedup 1.0000x reference)
//
#include <hip/hip_runtime.h>

#define TH 30
#define NT 512

typedef short bf16x8 __attribute__((ext_vector_type(8)));
typedef float f32x4 __attribute__((ext_vector_type(4)));
typedef unsigned short u16x4 __attribute__((ext_vector_type(4)));

// split f into bf16 hi + bf16 lo (truncation; lo compensates) ~2^-17 rel
__device__ __forceinline__ void f2hl(float f, unsigned short& h, unsigned short& l) {
  unsigned int ub = __float_as_uint(f);
  h = (unsigned short)(ub >> 16);
  float fh = __uint_as_float(ub & 0xffff0000u);
  l = (unsigned short)(__float_as_uint(f - fh) >> 16);
}
__device__ __forceinline__ float rec(unsigned short h, unsigned short l) {
  return __uint_as_float((unsigned int)h << 16) + __uint_as_float((unsigned int)l << 16);
}
// [R][64] ushort, granule-swizzled: (r,k) at r*64 + (((k>>3)^(r&7))<<3) + (k&7)
__device__ __forceinline__ bf16x8 ld64(const unsigned short* buf, int row, int kcg) {
  return *(const bf16x8*)(buf + row * 64 + ((kcg ^ (row & 7)) << 3));
}
__device__ __forceinline__ void st64_4(unsigned short* buf, int row, int col0, u16x4 v) {
  *(u16x4*)(buf + row * 64 + (((col0 >> 3) ^ (row & 7)) << 3) + (col0 & 7)) = v;
}
// K=16 tiles padded to stride 24 (48B rows: 16B-aligned, ~2-way banks max)
__device__ __forceinline__ bf16x8 ld24(const unsigned short* buf, int row, int g) {
  if (g < 2) return *(const bf16x8*)(buf + row * 24 + (g << 3));
  bf16x8 z = {};
  return z;
}
__device__ __forceinline__ void st24_4(unsigned short* buf, int row, int col0, u16x4 v) {
  *(u16x4*)(buf + row * 24 + col0) = v;
}
__device__ __forceinline__ bf16x8 ld16v(const unsigned short* buf, int row, int g) {
  if (g < 2) return *(const bf16x8*)(buf + row * 16 + (g << 3));
  bf16x8 z = {};
  return z;
}
__device__ __forceinline__ void cvt4(f32x4 a, u16x4& h, u16x4& l) {
  #pragma unroll
  for (int i = 0; i < 4; ++i) {
    unsigned short hh, ll;
    f2hl(a[i], hh, ll);
    h[i] = hh; l[i] = ll;
  }
}

#define MFMA3(ACC, XH, XL, YH, YL)                                        \
  ACC = __builtin_amdgcn_mfma_f32_16x16x32_bf16(XH, YH, ACC, 0, 0, 0);    \
  ACC = __builtin_amdgcn_mfma_f32_16x16x32_bf16(XH, YL, ACC, 0, 0, 0);    \
  ACC = __builtin_amdgcn_mfma_f32_16x16x32_bf16(XL, YH, ACC, 0, 0, 0);

__global__ __launch_bounds__(NT, 4) void lqr8(
    const float* __restrict__ gA, const float* __restrict__ gB,
    const float* __restrict__ gQ, const float* __restrict__ gR,
    const float* __restrict__ gG, float* __restrict__ gOut, int bsz)
{
  __shared__ unsigned short sVh[4096], sVl[4096];    // V (symmetric), swz
  __shared__ unsigned short sAth[4096], sAtl[4096];  // At[i][k]=A[k][i], swz
  __shared__ unsigned short sWth[4096], sWtl[4096];  // Wt[j][i]=W[i][j], swz (init: G rows)
  __shared__ unsigned short sBth[1024], sBtl[1024];  // Bt[u][k]=B[k][u], swz
  __shared__ unsigned short sVBh[1024], sVBl[1024];  // VBt[u][i]=(V*B)[i][u], swz
  __shared__ unsigned short sBWh[64 * 24], sBWl[64 * 24]; // [j][u]=BtW[u][j], pad24
  __shared__ unsigned short sKth[64 * 24], sKtl[64 * 24]; // [j][u]=-Kg[u][j], pad24
  __shared__ unsigned short sVIh[256], sVIl[256];    // Vuu^-1 (sym)
  __shared__ float sQG[31 * 64];
  __shared__ float sVuu[16 * 17];
  __shared__ float sMT[16 * 17];   // sMT[c][i] = (L^-1)[i][c]
  __shared__ float sVp[64];        // A^T v
  __shared__ float sKgv[16];       // kg
  __shared__ float sv[64];
  __shared__ float sBtv[16];

  const int b    = blockIdx.x;
  const int tid  = threadIdx.x;
  const int lane = tid & 63;
  const int wv   = tid >> 6;      // 0..7
  const int r    = lane & 15;
  const int g    = lane >> 4;
  const int it   = wv & 3;        // owned row-tile
  const int h    = wv >> 2;
  const int c0   = 2 * h, c1 = 2 * h + 1;  // owned col-tiles

  const float* Ab = gA + (size_t)b * 4096;
  const float* Bb = gB + (size_t)b * 1024;
  const float* Qb = gQ + (size_t)b * 4096;
  const float* Rb = gR + (size_t)b * 256;
  const float* Gb = gG + (size_t)b * ((TH + 1) * 64);

  // ---- stage + convert inputs ----
  for (int idx = tid; idx < 4096; idx += NT) {
    int k = idx >> 6, i = idx & 63;
    unsigned short hh, ll;
    f2hl(Ab[idx], hh, ll);
    int offA = i * 64 + (((k >> 3) ^ (i & 7)) << 3) + (k & 7);
    sAth[offA] = hh; sAtl[offA] = ll;
    f2hl(Qb[idx], hh, ll);
    int offV = k * 64 + (((i >> 3) ^ (k & 7)) << 3) + (i & 7);
    sVh[offV] = hh; sVl[offV] = ll;
  }
  for (int idx = tid; idx < 1024; idx += NT) {
    int k = idx >> 4, u = idx & 15;
    unsigned short hh, ll;
    f2hl(Bb[idx], hh, ll);
    int off = u * 64 + (((k >> 3) ^ (u & 7)) << 3) + (k & 7);
    sBth[off] = hh; sBtl[off] = ll;
  }
  for (int idx = tid; idx < 2048; idx += NT) {   // goals -> sWt temp rows 0..31
    int t = idx >> 6, k = idx & 63;
    float val = (t <= TH) ? Gb[idx] : 0.f;
    unsigned short hh, ll;
    f2hl(val, hh, ll);
    int off = t * 64 + (((k >> 3) ^ (t & 7)) << 3) + (k & 7);
    sWth[off] = hh; sWtl[off] = ll;
  }
  __syncthreads();

  // ---- QG via MFMA: qg[t][i] = sum_k G[t][k] Q[i][k] (Q sym) ----
  {
    f32x4 acc = {};
    #pragma unroll
    for (int kc = 0; kc < 2; ++kc) {
      int kcg = 4 * kc + g;
      bf16x8 xh = ld64(sWth, 16 * h + r, kcg);
      bf16x8 xl = ld64(sWtl, 16 * h + r, kcg);
      bf16x8 yh = ld64(sVh, 16 * it + r, kcg);
      bf16x8 yl = ld64(sVl, 16 * it + r, kcg);
      MFMA3(acc, xh, xl, yh, yl)
    }
    #pragma unroll
    for (int rg = 0; rg < 4; ++rg) {
      int tt = 16 * h + 4 * g + rg;
      if (tt <= TH) sQG[tt * 64 + 16 * it + r] = acc[rg];
    }
  }
  __syncthreads();
  if (tid < 64) sv[tid] = sQG[TH * 64 + tid];   // v0 = Q @ goals[:, T]

  f32x4 qreg0, qreg1, rreg;
  #pragma unroll
  for (int rg = 0; rg < 4; ++rg) {
    qreg0[rg] = Qb[(16 * it + 4 * g + rg) * 64 + 16 * c0 + r];
    qreg1[rg] = Qb[(16 * it + 4 * g + rg) * 64 + 16 * c1 + r];
    rreg[rg]  = Rb[(4 * g + rg) * 16 + r];
  }

  #pragma unroll 1
  for (int t = TH - 1; t >= 0; --t) {
    f32x4 vacc0 = qreg0, vacc1 = qreg1;  // Vnew accumulators (live across phases)

    auto ATW = [&]() {  // vacc += A^T W for owned subtiles (it, c0/c1)
      #pragma unroll
      for (int kc = 0; kc < 2; ++kc) {
        int kcg = 4 * kc + g;
        bf16x8 xh = ld64(sAth, 16 * it + r, kcg);
        bf16x8 xl = ld64(sAtl, 16 * it + r, kcg);
        bf16x8 yh = ld64(sWth, 16 * c0 + r, kcg);
        bf16x8 yl = ld64(sWtl, 16 * c0 + r, kcg);
        MFMA3(vacc0, xh, xl, yh, yl)
        yh = ld64(sWth, 16 * c1 + r, kcg);
        yl = ld64(sWtl, 16 * c1 + r, kcg);
        MFMA3(vacc1, xh, xl, yh, yl)
      }
    };

    // ===== P_A: W = V*A (subtiles it x {c0,c1}); VB = V*B (h==0 waves) =====
    {
      f32x4 aW0 = {}, aW1 = {}, aVB = {};
      #pragma unroll
      for (int kc = 0; kc < 2; ++kc) {
        int kcg = 4 * kc + g;
        bf16x8 xh = ld64(sVh, 16 * it + r, kcg);
        bf16x8 xl = ld64(sVl, 16 * it + r, kcg);
        bf16x8 yh = ld64(sAth, 16 * c0 + r, kcg);
        bf16x8 yl = ld64(sAtl, 16 * c0 + r, kcg);
        MFMA3(aW0, xh, xl, yh, yl)
        yh = ld64(sAth, 16 * c1 + r, kcg);
        yl = ld64(sAtl, 16 * c1 + r, kcg);
        MFMA3(aW1, xh, xl, yh, yl)
        if (h == 0) {
          yh = ld64(sBth, r, kcg);
          yl = ld64(sBtl, r, kcg);
          MFMA3(aVB, xh, xl, yh, yl)
        }
      }
      u16x4 h4, l4;
      cvt4(aW0, h4, l4); st64_4(sWth, 16 * c0 + r, 16 * it + 4 * g, h4); st64_4(sWtl, 16 * c0 + r, 16 * it + 4 * g, l4);
      cvt4(aW1, h4, l4); st64_4(sWth, 16 * c1 + r, 16 * it + 4 * g, h4); st64_4(sWtl, 16 * c1 + r, 16 * it + 4 * g, l4);
      if (h == 0) {
        cvt4(aVB, h4, l4); st64_4(sVBh, r, 16 * it + 4 * g, h4); st64_4(sVBl, r, 16 * it + 4 * g, l4);
      }
    }
    __syncthreads();

    // ===== P_B: Vuu(w0), Btv(w1), BtW(w2-5), start A^T W (w6,7) =====
    if (wv == 0) {
      f32x4 accU = rreg;
      #pragma unroll
      for (int kc = 0; kc < 2; ++kc) {
        int kcg = 4 * kc + g;
        bf16x8 xh = ld64(sBth, r, kcg);
        bf16x8 xl = ld64(sBtl, r, kcg);
        bf16x8 yh = ld64(sVBh, r, kcg);
        bf16x8 yl = ld64(sVBl, r, kcg);
        MFMA3(accU, xh, xl, yh, yl)
      }
      #pragma unroll
      for (int rg = 0; rg < 4; ++rg) sVuu[(4 * g + rg) * 17 + r] = accU[rg];
    } else if (wv == 1) {
      f32x4 accBv = {};
      #pragma unroll
      for (int kc = 0; kc < 2; ++kc) {
        int kcg = 4 * kc + g;
        bf16x8 xh = ld64(sBth, r, kcg);
        bf16x8 xl = ld64(sBtl, r, kcg);
        bf16x8 vh = {}, vl = {};
        if (r == 0) {
          #pragma unroll
          for (int e = 0; e < 8; ++e) {
            unsigned short hh, ll;
            f2hl(sv[32 * kc + 8 * g + e], hh, ll);
            vh[e] = (short)hh; vl[e] = (short)ll;
          }
        }
        MFMA3(accBv, xh, xl, vh, vl)
      }
      if (r == 0) {
        #pragma unroll
        for (int rg = 0; rg < 4; ++rg) sBtv[4 * g + rg] = accBv[rg];
      }
    } else if (wv <= 5) {
      const int c = wv - 2;
      f32x4 acc = {};
      #pragma unroll
      for (int kc = 0; kc < 2; ++kc) {
        int kcg = 4 * kc + g;
        bf16x8 xh = ld64(sBth, r, kcg);
        bf16x8 xl = ld64(sBtl, r, kcg);
        bf16x8 yh = ld64(sWth, 16 * c + r, kcg);
        bf16x8 yl = ld64(sWtl, 16 * c + r, kcg);
        MFMA3(acc, xh, xl, yh, yl)
      }
      u16x4 h4, l4; cvt4(acc, h4, l4);
      st24_4(sBWh, 16 * c + r, 4 * g, h4);
      st24_4(sBWl, 16 * c + r, 4 * g, l4);
    } else if (t > 0) {
      ATW();
    }
    __syncthreads();

    // ===== P_C: Cholesky+L^-1 (w0) || A^T W (w1-5) || Atv via MFMA (w6,7) =====
    if (wv == 0) {
      const int u = r;
      float rr[16];
      #pragma unroll
      for (int k = 0; k < 16; ++k) rr[k] = sVuu[u * 17 + k];
      #pragma unroll
      for (int j = 0; j < 16; ++j) {
        float s = rr[j];
        #pragma unroll
        for (int k = 0; k < j; ++k) s -= rr[k] * __shfl(rr[k], j);
        const float dj  = sqrtf(__shfl(s, j));
        const float inv = 1.f / dj;
        rr[j] = (u == j) ? dj : s * inv;
      }
      float idia[16];
      #pragma unroll
      for (int i = 0; i < 16; ++i) idia[i] = 1.f / __shfl(rr[i], i);
      float x[16];
      #pragma unroll
      for (int i = 0; i < 16; ++i) {
        float s = (i == u) ? 1.f : 0.f;
        #pragma unroll
        for (int k = 0; k < i; ++k) s -= __shfl(rr[k], i) * x[k];
        x[i] = s * idia[i];
      }
      if (lane < 16) {
        #pragma unroll
        for (int i = 0; i < 16; ++i) sMT[u * 17 + i] = x[i];
      }
    } else if (wv <= 5) {
      if (t > 0) ATW();
    } else if (t > 0) {
      const int rt0 = 2 * (wv - 6), rt1 = rt0 + 1;
      f32x4 at0 = {}, at1 = {};
      #pragma unroll
      for (int kc = 0; kc < 2; ++kc) {
        int kcg = 4 * kc + g;
        bf16x8 vh = {}, vl = {};
        if (r == 0) {
          #pragma unroll
          for (int e = 0; e < 8; ++e) {
            unsigned short hh, ll;
            f2hl(sv[32 * kc + 8 * g + e], hh, ll);
            vh[e] = (short)hh; vl[e] = (short)ll;
          }
        }
        bf16x8 xh = ld64(sAth, 16 * rt0 + r, kcg);
        bf16x8 xl = ld64(sAtl, 16 * rt0 + r, kcg);
        MFMA3(at0, xh, xl, vh, vl)
        xh = ld64(sAth, 16 * rt1 + r, kcg);
        xl = ld64(sAtl, 16 * rt1 + r, kcg);
        MFMA3(at1, xh, xl, vh, vl)
      }
      if (r == 0) {
        #pragma unroll
        for (int rg = 0; rg < 4; ++rg) {
          sVp[16 * rt0 + 4 * g + rg] = at0[rg];
          sVp[16 * rt1 + 4 * g + rg] = at1[rg];
        }
      }
    }
    __syncthreads();

    // ===== P_C2: VI = M^T M (w1,w2) || w0's A^T W =====
    if (wv == 1 || wv == 2) {
      const int e = (wv - 1) * 64 + lane;
      const int a2 = e & 15, b2 = e >> 4;   // b2: 0..7
      float s0 = 0.f, s1 = 0.f;
      #pragma unroll
      for (int i = 0; i < 16; ++i) {
        const float ma = sMT[a2 * 17 + i];
        s0 += ma * sMT[b2 * 17 + i];
        s1 += ma * sMT[(b2 + 8) * 17 + i];
      }
      unsigned short hh, ll;
      f2hl(s0, hh, ll); sVIh[a2 * 16 + b2] = hh;     sVIl[a2 * 16 + b2] = ll;
      f2hl(s1, hh, ll); sVIh[a2 * 16 + b2 + 8] = hh; sVIl[a2 * 16 + b2 + 8] = ll;
    } else if (wv == 0 && t > 0) {
      ATW();
    }
    __syncthreads();

    // ===== P_D: Kg = VI*BtW (w0-3, direct gOut store); kg (w4) =====
    const size_t obase = ((size_t)t * bsz + b) * (16 * 65);
    if (wv < 4) {
      const int c = wv;
      f32x4 acc = {};
      bf16x8 xh = ld16v(sVIh, r, g);
      bf16x8 xl = ld16v(sVIl, r, g);
      bf16x8 yh = ld24(sBWh, 16 * c + r, g);
      bf16x8 yl = ld24(sBWl, 16 * c + r, g);
      MFMA3(acc, xh, xl, yh, yl)
      f32x4 nacc = -acc;
      u16x4 h4, l4; cvt4(nacc, h4, l4);
      st24_4(sKth, 16 * c + r, 4 * g, h4);
      st24_4(sKtl, 16 * c + r, 4 * g, l4);
      #pragma unroll
      for (int rg = 0; rg < 4; ++rg)
        gOut[obase + (size_t)(4 * g + rg) * 65 + 16 * c + r] = acc[rg];
    } else if (wv == 4 && lane < 16) {
      float s = 0.f;
      #pragma unroll
      for (int w2 = 0; w2 < 16; ++w2)
        s += rec(sVIh[lane * 16 + w2], sVIl[lane * 16 + w2]) * sBtv[w2];
      sKgv[lane] = s;
      gOut[obase + (size_t)lane * 65 + 64] = s;
    }
    __syncthreads();

    // ===== P_E: Vnew -= BtW^T Kg, write V^T; v update (w5) =====
    if (t > 0) {
      {
        bf16x8 x2h = ld24(sBWh, 16 * it + r, g);
        bf16x8 x2l = ld24(sBWl, 16 * it + r, g);
        bf16x8 yh = ld24(sKth, 16 * c0 + r, g);
        bf16x8 yl = ld24(sKtl, 16 * c0 + r, g);
        MFMA3(vacc0, x2h, x2l, yh, yl)
        yh = ld24(sKth, 16 * c1 + r, g);
        yl = ld24(sKtl, 16 * c1 + r, g);
        MFMA3(vacc1, x2h, x2l, yh, yl)
      }
      u16x4 h4, l4;
      cvt4(vacc0, h4, l4); st64_4(sVh, 16 * c0 + r, 16 * it + 4 * g, h4); st64_4(sVl, 16 * c0 + r, 16 * it + 4 * g, l4);
      cvt4(vacc1, h4, l4); st64_4(sVh, 16 * c1 + r, 16 * it + 4 * g, h4); st64_4(sVl, 16 * c1 + r, 16 * it + 4 * g, l4);
      if (wv == 5) {
        const int i = lane;
        float s = sQG[t * 64 + i] + sVp[i];
        #pragma unroll
        for (int u2 = 0; u2 < 16; ++u2)
          s -= rec(sBWh[i * 24 + u2], sBWl[i * 24 + u2]) * sKgv[u2];
        sv[i] = s;   // v_new = qg + A^T v - BtW^T kg
      }
    }
    __syncthreads();
  }
}

extern "C" void kernel_launch(void* const* d_in, const int* in_sizes, int n_in,
                              void* d_out, int out_size, void* d_ws, size_t ws_size,
                              hipStream_t stream) {
  (void)n_in; (void)out_size; (void)d_ws; (void)ws_size;
  const float* A = (const float*)d_in[0];
  const float* B = (const float*)d_in[1];
  const float* Q = (const float*)d_in[2];
  const float* R = (const float*)d_in[3];
  const float* G = (const float*)d_in[4];
  float* out = (float*)d_out;
  const int bsz = in_sizes[3] / 256;   // R is bsz*16*16
  lqr8<<<bsz, NT, 0, stream>>>(A, B, Q, R, G, out, bsz);
}

// Round 4
// 1665.086 us; speedup vs baseline: 1.2374x; 1.2374x over previous
//
#include <hip/hip_runtime.h>

#define TH 30
#define NT 256

typedef short bf16x8 __attribute__((ext_vector_type(8)));
typedef float f32x4 __attribute__((ext_vector_type(4)));
typedef unsigned short u16x4 __attribute__((ext_vector_type(4)));
typedef unsigned int u32x4 __attribute__((ext_vector_type(4)));

// split f into bf16 hi + bf16 lo (truncation; lo compensates) ~2^-17 rel
__device__ __forceinline__ void f2hl(float f, unsigned short& h, unsigned short& l) {
  unsigned int ub = __float_as_uint(f);
  h = (unsigned short)(ub >> 16);
  float fh = __uint_as_float(ub & 0xffff0000u);
  l = (unsigned short)(__float_as_uint(f - fh) >> 16);
}
// [R][64] ushort, granule-swizzled: (r,k) at r*64 + (((k>>3)^(r&7))<<3) + (k&7)
__device__ __forceinline__ bf16x8 ld64(const unsigned short* buf, int row, int kcg) {
  return *(const bf16x8*)(buf + row * 64 + ((kcg ^ (row & 7)) << 3));
}
__device__ __forceinline__ void st64_4(unsigned short* buf, int row, int col0, u16x4 v) {
  *(u16x4*)(buf + row * 64 + (((col0 >> 3) ^ (row & 7)) << 3) + (col0 & 7)) = v;
}
// K=16 tiles padded to stride 24 (48B rows); g>=2 -> zero frags (K padding)
__device__ __forceinline__ bf16x8 ld24(const unsigned short* buf, int row, int g) {
  if (g < 2) return *(const bf16x8*)(buf + row * 24 + (g << 3));
  bf16x8 z = {};
  return z;
}
__device__ __forceinline__ void st24_4(unsigned short* buf, int row, int col0, u16x4 v) {
  *(u16x4*)(buf + row * 24 + col0) = v;
}
__device__ __forceinline__ void cvt4(f32x4 a, u16x4& h, u16x4& l) {
  #pragma unroll
  for (int i = 0; i < 4; ++i) {
    unsigned short hh, ll;
    f2hl(a[i], hh, ll);
    h[i] = hh; l[i] = ll;
  }
}
__device__ __forceinline__ bf16x8 negbf(bf16x8 v) {  // flip bf16 sign bits
  u32x4 u = __builtin_bit_cast(u32x4, v);
  u ^= 0x80008000u;
  return __builtin_bit_cast(bf16x8, u);
}

#define MFMA3(ACC, XH, XL, YH, YL)                                        \
  ACC = __builtin_amdgcn_mfma_f32_16x16x32_bf16(XH, YH, ACC, 0, 0, 0);    \
  ACC = __builtin_amdgcn_mfma_f32_16x16x32_bf16(XH, YL, ACC, 0, 0, 0);    \
  ACC = __builtin_amdgcn_mfma_f32_16x16x32_bf16(XL, YH, ACC, 0, 0, 0);

__global__ __launch_bounds__(NT, 2) void lqr4(
    const float* __restrict__ gA, const float* __restrict__ gB,
    const float* __restrict__ gQ, const float* __restrict__ gR,
    const float* __restrict__ gG, float* __restrict__ gOut, int bsz)
{
  __shared__ unsigned short sVh[4096], sVl[4096];    // V row-major (sym), swz
  __shared__ unsigned short sAth[4096], sAtl[4096];  // At[i][k]=A[k][i], swz
  __shared__ unsigned short sWth[4096], sWtl[4096];  // Wt[j][i]=W[i][j], swz (init: goals)
  __shared__ unsigned short sBth[1024], sBtl[1024];  // Bt[u][k]=B[k][u], swz
  __shared__ unsigned short sVBh[1024], sVBl[1024];  // VBt[u][i]=(V*B)[i][u], swz
  __shared__ unsigned short sBWh[1536], sBWl[1536];  // [j][u]=BtW[u][j], pad24
  __shared__ unsigned short sSh[1536],  sSl[1536];   // [j][u]=S[u][j],  pad24  (S=M*BtW)
  __shared__ unsigned short sMth[384],  sMtl[384];   // [u][w]=M[w][u], pad24
  __shared__ unsigned short sMbh[384],  sMbl[384];   // [u][w]=M[u][w], pad24
  __shared__ float sQG[31 * 64];
  __shared__ float sVuu[16 * 17];
  __shared__ float sMT[16 * 17];   // sMT[c][i] = M[i][c]  (fp32)
  __shared__ float sVp[64];        // A^T v
  __shared__ float sw_[16];        // w~ = M * Btv
  __shared__ float sv[64];
  __shared__ float sBtv[16];

  const int b    = blockIdx.x;
  const int tid  = threadIdx.x;
  const int lane = tid & 63;
  const int wv   = tid >> 6;      // 0..3
  const int r    = lane & 15;
  const int g    = lane >> 4;
  const int it   = wv;            // owned row-tile

  const float* Ab = gA + (size_t)b * 4096;
  const float* Bb = gB + (size_t)b * 1024;
  const float* Qb = gQ + (size_t)b * 4096;
  const float* Rb = gR + (size_t)b * 256;
  const float* Gb = gG + (size_t)b * ((TH + 1) * 64);

  // ---- stage + convert inputs ----
  for (int idx = tid; idx < 4096; idx += NT) {
    int k = idx >> 6, i = idx & 63;
    unsigned short hh, ll;
    f2hl(Ab[idx], hh, ll);
    int offA = i * 64 + (((k >> 3) ^ (i & 7)) << 3) + (k & 7);
    sAth[offA] = hh; sAtl[offA] = ll;
    f2hl(Qb[idx], hh, ll);
    int offV = k * 64 + (((i >> 3) ^ (k & 7)) << 3) + (i & 7);
    sVh[offV] = hh; sVl[offV] = ll;
  }
  for (int idx = tid; idx < 1024; idx += NT) {
    int k = idx >> 4, u = idx & 15;
    unsigned short hh, ll;
    f2hl(Bb[idx], hh, ll);
    int off = u * 64 + (((k >> 3) ^ (u & 7)) << 3) + (k & 7);
    sBth[off] = hh; sBtl[off] = ll;
  }
  for (int idx = tid; idx < 2048; idx += NT) {   // goals -> sWt temp rows 0..31
    int tg = idx >> 6, k = idx & 63;
    float val = (tg <= TH) ? Gb[idx] : 0.f;
    unsigned short hh, ll;
    f2hl(val, hh, ll);
    int off = tg * 64 + (((k >> 3) ^ (tg & 7)) << 3) + (k & 7);
    sWth[off] = hh; sWtl[off] = ll;
  }
  __syncthreads();

  // ---- QG via MFMA: qg[t'][i] = sum_k G[t'][k] Q[i][k] (Q sym) ----
  {
    const int tt = wv >> 1;
    #pragma unroll
    for (int ci = 0; ci < 2; ++ci) {
      const int ic = 2 * (wv & 1) + ci;
      f32x4 acc = {};
      #pragma unroll
      for (int kc = 0; kc < 2; ++kc) {
        int kcg = 4 * kc + g;
        bf16x8 xh = ld64(sWth, 16 * tt + r, kcg);
        bf16x8 xl = ld64(sWtl, 16 * tt + r, kcg);
        bf16x8 yh = ld64(sVh, 16 * ic + r, kcg);
        bf16x8 yl = ld64(sVl, 16 * ic + r, kcg);
        MFMA3(acc, xh, xl, yh, yl)
      }
      #pragma unroll
      for (int rg = 0; rg < 4; ++rg) {
        int t2 = 16 * tt + 4 * g + rg;
        if (t2 <= TH) sQG[t2 * 64 + 16 * ic + r] = acc[rg];
      }
    }
  }
  __syncthreads();
  if (tid < 64) sv[tid] = sQG[TH * 64 + tid];   // v0 = Q @ goals[:, T]

  // ---- persistent frags & constants ----
  f32x4 qreg[4], rreg;
  #pragma unroll
  for (int c = 0; c < 4; ++c)
    #pragma unroll
    for (int rg = 0; rg < 4; ++rg)
      qreg[c][rg] = Qb[(16 * it + 4 * g + rg) * 64 + 16 * c + r];
  #pragma unroll
  for (int rg = 0; rg < 4; ++rg) rreg[rg] = Rb[(4 * g + rg) * 16 + r];
  bf16x8 btf_h[2], btf_l[2], atf_h[2], atf_l[2];
  #pragma unroll
  for (int kc = 0; kc < 2; ++kc) {
    btf_h[kc] = ld64(sBth, r, 4 * kc + g);
    btf_l[kc] = ld64(sBtl, r, 4 * kc + g);
    atf_h[kc] = ld64(sAth, 16 * it + r, 4 * kc + g);
    atf_l[kc] = ld64(sAtl, 16 * it + r, 4 * kc + g);
  }

  #pragma unroll 1
  for (int t = TH - 1; t >= 0; --t) {
    const size_t obase = ((size_t)t * bsz + b) * (16 * 65);
    f32x4 vacc[4];
    #pragma unroll
    for (int c = 0; c < 4; ++c) vacc[c] = qreg[c];

    auto ATW = [&](int kc) {   // vacc[c] += (A^T W) subtiles (it, c)
      const int kcg = 4 * kc + g;
      const bf16x8 xh = atf_h[kc], xl = atf_l[kc];
      #pragma unroll
      for (int c = 0; c < 4; ++c) {
        bf16x8 yh = ld64(sWth, 16 * c + r, kcg);
        bf16x8 yl = ld64(sWtl, 16 * c + r, kcg);
        MFMA3(vacc[c], xh, xl, yh, yl)
      }
    };

    // ===== P_A: W = V*A (row-tile it x all cols) ; VB row-tile =====
    {
      f32x4 aW[4] = {}, aVB = {};
      #pragma unroll
      for (int kc = 0; kc < 2; ++kc) {
        int kcg = 4 * kc + g;
        bf16x8 xh = ld64(sVh, 16 * it + r, kcg);
        bf16x8 xl = ld64(sVl, 16 * it + r, kcg);
        #pragma unroll
        for (int c = 0; c < 4; ++c) {
          bf16x8 yh = ld64(sAth, 16 * c + r, kcg);
          bf16x8 yl = ld64(sAtl, 16 * c + r, kcg);
          MFMA3(aW[c], xh, xl, yh, yl)
        }
        MFMA3(aVB, xh, xl, btf_h[kc], btf_l[kc])
      }
      u16x4 h4, l4;
      #pragma unroll
      for (int c = 0; c < 4; ++c) {
        cvt4(aW[c], h4, l4);
        st64_4(sWth, 16 * c + r, 16 * it + 4 * g, h4);
        st64_4(sWtl, 16 * c + r, 16 * it + 4 * g, l4);
      }
      cvt4(aVB, h4, l4);
      st64_4(sVBh, r, 16 * it + 4 * g, h4);
      st64_4(sVBl, r, 16 * it + 4 * g, l4);
    }
    __syncthreads();

    // ===== P_B: Vuu(w0) | Btv(w1) | BtW(w2,w3) ; all: ATW kc=0 =====
    if (wv == 0) {
      f32x4 accU = rreg;
      #pragma unroll
      for (int kc = 0; kc < 2; ++kc) {
        bf16x8 yh = ld64(sVBh, r, 4 * kc + g);
        bf16x8 yl = ld64(sVBl, r, 4 * kc + g);
        MFMA3(accU, btf_h[kc], btf_l[kc], yh, yl)
      }
      #pragma unroll
      for (int rg = 0; rg < 4; ++rg) sVuu[(4 * g + rg) * 17 + r] = accU[rg];
    } else if (wv == 1) {
      f32x4 accBv = {};
      #pragma unroll
      for (int kc = 0; kc < 2; ++kc) {
        bf16x8 vh = {}, vl = {};
        if (r == 0) {
          #pragma unroll
          for (int e = 0; e < 8; ++e) {
            unsigned short hh, ll;
            f2hl(sv[32 * kc + 8 * g + e], hh, ll);
            vh[e] = (short)hh; vl[e] = (short)ll;
          }
        }
        MFMA3(accBv, btf_h[kc], btf_l[kc], vh, vl)
      }
      if (r == 0) {
        #pragma unroll
        for (int rg = 0; rg < 4; ++rg) sBtv[4 * g + rg] = accBv[rg];
      }
    } else {
      const int cb = 2 * (wv - 2);
      #pragma unroll
      for (int ci = 0; ci < 2; ++ci) {
        const int c = cb + ci;
        f32x4 acc = {};
        #pragma unroll
        for (int kc = 0; kc < 2; ++kc) {
          bf16x8 yh = ld64(sWth, 16 * c + r, 4 * kc + g);
          bf16x8 yl = ld64(sWtl, 16 * c + r, 4 * kc + g);
          MFMA3(acc, btf_h[kc], btf_l[kc], yh, yl)
        }
        u16x4 h4, l4; cvt4(acc, h4, l4);
        st24_4(sBWh, 16 * c + r, 4 * g, h4);
        st24_4(sBWl, 16 * c + r, 4 * g, l4);
      }
    }
    if (t > 0) ATW(0);
    __syncthreads();

    // ===== P_C: chol+M (w0) | ATW kc1 + Atv (w1,w2) | ATW kc1 (w3) =====
    if (wv == 0) {
      const int u = r;
      float rr[16];
      #pragma unroll
      for (int k = 0; k < 16; ++k) rr[k] = sVuu[u * 17 + k];
      #pragma unroll
      for (int j = 0; j < 16; ++j) {
        float s = rr[j];
        #pragma unroll
        for (int k = 0; k < j; ++k) s -= rr[k] * __shfl(rr[k], j);
        const float dj  = sqrtf(__shfl(s, j));
        const float inv = 1.f / dj;
        rr[j] = (u == j) ? dj : s * inv;
      }
      float idia[16];
      #pragma unroll
      for (int i = 0; i < 16; ++i) idia[i] = 1.f / __shfl(rr[i], i);
      float x[16];
      #pragma unroll
      for (int i = 0; i < 16; ++i) {
        float s = (i == u) ? 1.f : 0.f;
        #pragma unroll
        for (int k = 0; k < i; ++k) s -= __shfl(rr[k], i) * x[k];
        x[i] = s * idia[i];
      }
      if (lane < 16) {   // lane u holds column u of M: x[i] = M[i][u]
        #pragma unroll
        for (int i = 0; i < 16; ++i) {
          sMT[u * 17 + i] = x[i];
          unsigned short hh, ll;
          f2hl(x[i], hh, ll);
          sMth[u * 24 + i] = hh; sMtl[u * 24 + i] = ll;  // Mt[u][i]=M[i][u]
          sMbh[i * 24 + u] = hh; sMbl[i * 24 + u] = ll;  // Mb[i][u]=M[i][u]
        }
      }
    } else if (wv <= 2) {
      if (t > 0) {
        ATW(1);
        const int rb = 2 * (wv - 1);
        f32x4 at0 = {}, at1 = {};
        #pragma unroll
        for (int kc = 0; kc < 2; ++kc) {
          int kcg = 4 * kc + g;
          bf16x8 vh = {}, vl = {};
          if (r == 0) {
            #pragma unroll
            for (int e = 0; e < 8; ++e) {
              unsigned short hh, ll;
              f2hl(sv[32 * kc + 8 * g + e], hh, ll);
              vh[e] = (short)hh; vl[e] = (short)ll;
            }
          }
          bf16x8 xh = ld64(sAth, 16 * rb + r, kcg);
          bf16x8 xl = ld64(sAtl, 16 * rb + r, kcg);
          MFMA3(at0, xh, xl, vh, vl)
          xh = ld64(sAth, 16 * (rb + 1) + r, kcg);
          xl = ld64(sAtl, 16 * (rb + 1) + r, kcg);
          MFMA3(at1, xh, xl, vh, vl)
        }
        if (r == 0) {
          #pragma unroll
          for (int rg = 0; rg < 4; ++rg) {
            sVp[16 * rb + 4 * g + rg]       = at0[rg];
            sVp[16 * (rb + 1) + 4 * g + rg] = at1[rg];
          }
        }
      }
    } else {
      if (t > 0) ATW(1);
    }
    __syncthreads();

    // ===== P_C2+D: S=M*BtW then Kg=Mt*S -> gOut (w1,w2) | w~,kg (w3) | ATW kc1 (w0) =====
    if (wv == 0) {
      if (t > 0) ATW(1);
    } else if (wv <= 2) {
      const int cb = 2 * (wv - 1);
      #pragma unroll
      for (int ci = 0; ci < 2; ++ci) {
        const int c = cb + ci;
        f32x4 sacc = {};
        {
          bf16x8 xh = ld24(sMbh, r, g), xl = ld24(sMbl, r, g);
          bf16x8 yh = ld24(sBWh, 16 * c + r, g), yl = ld24(sBWl, 16 * c + r, g);
          MFMA3(sacc, xh, xl, yh, yl)       // D[u][j] = S[u][j]
        }
        u16x4 h4, l4; cvt4(sacc, h4, l4);
        st24_4(sSh, 16 * c + r, 4 * g, h4); // sSt[j][u] = S[u][j]
        st24_4(sSl, 16 * c + r, 4 * g, l4);
        f32x4 kacc = {};
        {
          bf16x8 xh = ld24(sMth, r, g), xl = ld24(sMtl, r, g);
          bf16x8 yh = ld24(sSh, 16 * c + r, g), yl = ld24(sSl, 16 * c + r, g);
          MFMA3(kacc, xh, xl, yh, yl)       // D[u][j] = Kg[u][j]
        }
        #pragma unroll
        for (int rg = 0; rg < 4; ++rg)
          gOut[obase + (size_t)(4 * g + rg) * 65 + 16 * c + r] = kacc[rg];
      }
    } else {
      if (lane < 16) {
        float wt_ = 0.f;
        #pragma unroll
        for (int u2 = 0; u2 < 16; ++u2)
          wt_ += sMT[u2 * 17 + lane] * sBtv[u2];   // w~ = M * Btv
        sw_[lane] = wt_;
        float kgv = 0.f;
        #pragma unroll
        for (int w2 = 0; w2 < 16; ++w2)
          kgv += __shfl(wt_, w2) * sMT[lane * 17 + w2];  // kg = M^T w~
        gOut[obase + (size_t)lane * 65 + 64] = kgv;
      }
    }
    __syncthreads();

    // ===== P_E: Vnew = Q + A^T W - S^T S ; v update (w3) =====
    if (t > 0) {
      bf16x8 xnh = negbf(ld24(sSh, 16 * it + r, g));
      bf16x8 xnl = negbf(ld24(sSl, 16 * it + r, g));
      u16x4 h4, l4;
      #pragma unroll
      for (int c = 0; c < 4; ++c) {
        bf16x8 yh = ld24(sSh, 16 * c + r, g);
        bf16x8 yl = ld24(sSl, 16 * c + r, g);
        MFMA3(vacc[c], xnh, xnl, yh, yl)
        cvt4(vacc[c], h4, l4);
        st64_4(sVh, 16 * c + r, 16 * it + 4 * g, h4);
        st64_4(sVl, 16 * c + r, 16 * it + 4 * g, l4);
      }
      if (wv == 3) {
        bf16x8 wh = {}, wl = {};
        if (r == 0 && g < 2) {
          #pragma unroll
          for (int e = 0; e < 8; ++e) {
            unsigned short hh, ll;
            f2hl(sw_[8 * g + e], hh, ll);
            wh[e] = (short)hh; wl[e] = (short)ll;
          }
        }
        #pragma unroll
        for (int c = 0; c < 4; ++c) {
          bf16x8 yh = ld24(sSh, 16 * c + r, g);
          bf16x8 yl = ld24(sSl, 16 * c + r, g);
          f32x4 vt = {};
          MFMA3(vt, wh, wl, yh, yl)        // D[0][i] = (S^T w~)[i]
          if (g == 0) {
            const int i = 16 * c + r;
            sv[i] = sQG[t * 64 + i] + sVp[i] - vt[0];
          }
        }
      }
    }
    __syncthreads();
  }
}

extern "C" void kernel_launch(void* const* d_in, const int* in_sizes, int n_in,
                              void* d_out, int out_size, void* d_ws, size_t ws_size,
                              hipStream_t stream) {
  (void)n_in; (void)out_size; (void)d_ws; (void)ws_size;
  const float* A = (const float*)d_in[0];
  const float* B = (const float*)d_in[1];
  const float* Q = (const float*)d_in[2];
  const float* R = (const float*)d_in[3];
  const float* G = (const float*)d_in[4];
  float* out = (float*)d_out;
  const int bsz = in_sizes[3] / 256;   // R is bsz*16*16
  lqr4<<<bsz, NT, 0, stream>>>(A, B, Q, R, G, out, bsz);
}

// Round 5
// 1284.380 us; speedup vs baseline: 1.6042x; 1.2964x over previous
//
#include <hip/hip_runtime.h>

#define TH 30
#define NT 256

typedef short bf16x8 __attribute__((ext_vector_type(8)));
typedef float f32x4 __attribute__((ext_vector_type(4)));
typedef unsigned short u16x4 __attribute__((ext_vector_type(4)));
typedef unsigned int u32x4 __attribute__((ext_vector_type(4)));

// split f into bf16 hi + bf16 lo (truncation; lo compensates) ~2^-17 rel
__device__ __forceinline__ void f2hl(float f, unsigned short& h, unsigned short& l) {
  unsigned int ub = __float_as_uint(f);
  h = (unsigned short)(ub >> 16);
  float fh = __uint_as_float(ub & 0xffff0000u);
  l = (unsigned short)(__float_as_uint(f - fh) >> 16);
}
__device__ __forceinline__ float rec(unsigned short h, unsigned short l) {
  return __uint_as_float((unsigned int)h << 16) + __uint_as_float((unsigned int)l << 16);
}
// [R][64] ushort, granule-swizzled: (r,k) at r*64 + (((k>>3)^(r&7))<<3) + (k&7)
__device__ __forceinline__ bf16x8 ld64(const unsigned short* buf, int row, int kcg) {
  return *(const bf16x8*)(buf + row * 64 + ((kcg ^ (row & 7)) << 3));
}
__device__ __forceinline__ void st64_4(unsigned short* buf, int row, int col0, u16x4 v) {
  *(u16x4*)(buf + row * 64 + (((col0 >> 3) ^ (row & 7)) << 3) + (col0 & 7)) = v;
}
// K=16 tiles, stride 16 (32B rows); g>=2 -> zero frags (K padding)
__device__ __forceinline__ bf16x8 ld16s(const unsigned short* buf, int row, int g) {
  if (g < 2) return *(const bf16x8*)(buf + row * 16 + (g << 3));
  bf16x8 z = {};
  return z;
}
__device__ __forceinline__ void st16s(unsigned short* buf, int row, int col0, u16x4 v) {
  *(u16x4*)(buf + row * 16 + col0) = v;
}
__device__ __forceinline__ void cvt4(f32x4 a, u16x4& h, u16x4& l) {
  #pragma unroll
  for (int i = 0; i < 4; ++i) {
    unsigned short hh, ll;
    f2hl(a[i], hh, ll);
    h[i] = hh; l[i] = ll;
  }
}
__device__ __forceinline__ bf16x8 negbf(bf16x8 v) {  // flip bf16 sign bits
  u32x4 u = __builtin_bit_cast(u32x4, v);
  u ^= 0x80008000u;
  return __builtin_bit_cast(bf16x8, u);
}

#define MFMA3(ACC, XH, XL, YH, YL)                                        \
  ACC = __builtin_amdgcn_mfma_f32_16x16x32_bf16(XH, YH, ACC, 0, 0, 0);    \
  ACC = __builtin_amdgcn_mfma_f32_16x16x32_bf16(XH, YL, ACC, 0, 0, 0);    \
  ACC = __builtin_amdgcn_mfma_f32_16x16x32_bf16(XL, YH, ACC, 0, 0, 0);
#define MFMA2L(ACC, XH, YH, YL)                                           \
  ACC = __builtin_amdgcn_mfma_f32_16x16x32_bf16(XH, YH, ACC, 0, 0, 0);    \
  ACC = __builtin_amdgcn_mfma_f32_16x16x32_bf16(XH, YL, ACC, 0, 0, 0);
#define MFMA2R(ACC, XH, XL, YH)                                           \
  ACC = __builtin_amdgcn_mfma_f32_16x16x32_bf16(XH, YH, ACC, 0, 0, 0);    \
  ACC = __builtin_amdgcn_mfma_f32_16x16x32_bf16(XL, YH, ACC, 0, 0, 0);
#define MFMA1(ACC, XH, YH)                                                \
  ACC = __builtin_amdgcn_mfma_f32_16x16x32_bf16(XH, YH, ACC, 0, 0, 0);

// LDS plan (bytes, 16B aligned, total 53952 -> alloc 54272 -> 3 blocks/CU)
#define O_VH   0
#define O_VL   8192
#define O_WTH  16384
#define O_WTL  24576
#define O_ATH  32768
#define O_BTH  40960
#define O_VBH  43008
#define O_BWH  45056   /* 64x16 u16; S^T hi in-place */
#define O_BWL  47104   /* S^T lo in-place */
#define O_MTH  49152
#define O_MTL  49664
#define O_MBH  50176
#define O_MBL  50688
#define O_VUU  51200   /* f32 16x17 */
#define O_MT   52288   /* f32 16x17 */
#define O_VP   53376   /* f32 64 */
#define O_SV   53632   /* f32 64 */
#define O_BTV  53888   /* f32 16 */
#define SMEM_BYTES 53952

__global__ __launch_bounds__(NT, 3) void lqr5(
    const float* __restrict__ gA, const float* __restrict__ gB,
    const float* __restrict__ gQ, const float* __restrict__ gR,
    const float* __restrict__ gG, float* __restrict__ gOut, int bsz)
{
  __shared__ __align__(16) unsigned char smem[SMEM_BYTES];
  unsigned short* sVh  = (unsigned short*)(smem + O_VH);
  unsigned short* sVl  = (unsigned short*)(smem + O_VL);
  unsigned short* sWth = (unsigned short*)(smem + O_WTH);
  unsigned short* sWtl = (unsigned short*)(smem + O_WTL);
  unsigned short* sAth = (unsigned short*)(smem + O_ATH);
  unsigned short* sBth = (unsigned short*)(smem + O_BTH);
  unsigned short* sVBh = (unsigned short*)(smem + O_VBH);
  unsigned short* sBWh = (unsigned short*)(smem + O_BWH);
  unsigned short* sBWl = (unsigned short*)(smem + O_BWL);
  unsigned short* sMth = (unsigned short*)(smem + O_MTH);
  unsigned short* sMtl = (unsigned short*)(smem + O_MTL);
  unsigned short* sMbh = (unsigned short*)(smem + O_MBH);
  unsigned short* sMbl = (unsigned short*)(smem + O_MBL);
  float* sVuu = (float*)(smem + O_VUU);
  float* sMT  = (float*)(smem + O_MT);
  float* sVp  = (float*)(smem + O_VP);
  float* sv   = (float*)(smem + O_SV);
  float* sBtv = (float*)(smem + O_BTV);

  const int b    = blockIdx.x;
  const int tid  = threadIdx.x;
  const int lane = tid & 63;
  const int wv   = tid >> 6;      // 0..3
  const int r    = lane & 15;
  const int g    = lane >> 4;
  const int it   = wv;            // owned row-tile

  const float* Ab = gA + (size_t)b * 4096;
  const float* Bb = gB + (size_t)b * 1024;
  const float* Qb = gQ + (size_t)b * 4096;
  const float* Rb = gR + (size_t)b * 256;
  const float* Gb = gG + (size_t)b * ((TH + 1) * 64);

  // ---- stage + convert inputs (A,B hi only; V,W-goals hi+lo) ----
  for (int idx = tid; idx < 4096; idx += NT) {
    int k = idx >> 6, i = idx & 63;
    unsigned short hh, ll;
    f2hl(Ab[idx], hh, ll);
    sAth[i * 64 + (((k >> 3) ^ (i & 7)) << 3) + (k & 7)] = hh;
    f2hl(Qb[idx], hh, ll);
    int offV = k * 64 + (((i >> 3) ^ (k & 7)) << 3) + (i & 7);
    sVh[offV] = hh; sVl[offV] = ll;
  }
  for (int idx = tid; idx < 1024; idx += NT) {
    int k = idx >> 4, u = idx & 15;
    unsigned short hh, ll;
    f2hl(Bb[idx], hh, ll);
    sBth[u * 64 + (((k >> 3) ^ (u & 7)) << 3) + (k & 7)] = hh;
  }
  for (int idx = tid; idx < 2048; idx += NT) {   // goals -> sWt temp rows 0..31
    int tg = idx >> 6, k = idx & 63;
    float val = (tg <= TH) ? Gb[idx] : 0.f;
    unsigned short hh, ll;
    f2hl(val, hh, ll);
    int off = tg * 64 + (((k >> 3) ^ (tg & 7)) << 3) + (k & 7);
    sWth[off] = hh; sWtl[off] = ll;
  }
  __syncthreads();

  // ---- QG via MFMA: qg[t'][i] = sum_k G[t'][k] Q[i][k]; stash into gOut slots ----
  {
    const int tt = wv >> 1;
    #pragma unroll
    for (int ci = 0; ci < 2; ++ci) {
      const int ic = 2 * (wv & 1) + ci;
      f32x4 acc = {};
      #pragma unroll
      for (int kc = 0; kc < 2; ++kc) {
        int kcg = 4 * kc + g;
        bf16x8 xh = ld64(sWth, 16 * tt + r, kcg);
        bf16x8 xl = ld64(sWtl, 16 * tt + r, kcg);
        bf16x8 yh = ld64(sVh, 16 * ic + r, kcg);
        bf16x8 yl = ld64(sVl, 16 * ic + r, kcg);
        MFMA3(acc, xh, xl, yh, yl)
      }
      #pragma unroll
      for (int rg = 0; rg < 4; ++rg) {
        int t2 = 16 * tt + 4 * g + rg;
        int i2 = 16 * ic + r;
        if (t2 < TH) gOut[((size_t)t2 * bsz + b) * 1040 + i2] = acc[rg];
        else if (t2 == TH) sv[i2] = acc[rg];   // v0 = Q @ goals[:, T]
      }
    }
  }

  // ---- persistent frags & constants (reads of sAth/sBth are post-barrier) ----
  f32x4 qreg[4], rreg;
  #pragma unroll
  for (int c = 0; c < 4; ++c)
    #pragma unroll
    for (int rg = 0; rg < 4; ++rg)
      qreg[c][rg] = Qb[(16 * it + 4 * g + rg) * 64 + 16 * c + r];
  #pragma unroll
  for (int rg = 0; rg < 4; ++rg) rreg[rg] = Rb[(4 * g + rg) * 16 + r];
  bf16x8 btf_h[2], atf_h[2];
  #pragma unroll
  for (int kc = 0; kc < 2; ++kc) {
    btf_h[kc] = ld64(sBth, r, 4 * kc + g);
    atf_h[kc] = ld64(sAth, 16 * it + r, 4 * kc + g);
  }
  __syncthreads();

  float wt_ = 0.f;   // w~ = M*Btv, lives in w3 lanes<16 across P_D->P_E

  #pragma unroll 1
  for (int t = TH - 1; t >= 0; --t) {
    const size_t obase = ((size_t)t * bsz + b) * 1040;
    float qgt = 0.f;
    if (wv == 3) qgt = gOut[obase + lane];   // early read of QG stash (pre-P_D)
    f32x4 vacc[4];
    #pragma unroll
    for (int c = 0; c < 4; ++c) vacc[c] = qreg[c];

    auto ATW = [&](int kc) {   // vacc[c] += (A^T W) subtiles (it, c)
      const int kcg = 4 * kc + g;
      const bf16x8 xh = atf_h[kc];
      #pragma unroll
      for (int c = 0; c < 4; ++c) {
        bf16x8 yh = ld64(sWth, 16 * c + r, kcg);
        bf16x8 yl = ld64(sWtl, 16 * c + r, kcg);
        MFMA2L(vacc[c], xh, yh, yl)
      }
    };

    // ===== P_A: W = V*A (row-tile it x all cols, hi+lo out); VB (hi out) =====
    {
      f32x4 aW[4] = {}, aVB = {};
      #pragma unroll
      for (int kc = 0; kc < 2; ++kc) {
        int kcg = 4 * kc + g;
        bf16x8 xh = ld64(sVh, 16 * it + r, kcg);
        bf16x8 xl = ld64(sVl, 16 * it + r, kcg);
        #pragma unroll
        for (int c = 0; c < 4; ++c) {
          bf16x8 yh = ld64(sAth, 16 * c + r, kcg);
          MFMA2R(aW[c], xh, xl, yh)
        }
        MFMA2R(aVB, xh, xl, btf_h[kc])
      }
      u16x4 h4, l4;
      #pragma unroll
      for (int c = 0; c < 4; ++c) {
        cvt4(aW[c], h4, l4);
        st64_4(sWth, 16 * c + r, 16 * it + 4 * g, h4);
        st64_4(sWtl, 16 * c + r, 16 * it + 4 * g, l4);
      }
      cvt4(aVB, h4, l4);
      st64_4(sVBh, r, 16 * it + 4 * g, h4);
    }
    __syncthreads();

    // ===== P_B: Vuu+Btv (w0) | BtW (w1:{0,3}, w2:{1}, w3:{2}) ; all: ATW(0) =====
    if (wv == 0) {
      f32x4 accU = rreg, accBv = {};
      #pragma unroll
      for (int kc = 0; kc < 2; ++kc) {
        MFMA1(accU, btf_h[kc], ld64(sVBh, r, 4 * kc + g))
        bf16x8 vh = {}, vl = {};
        if (r == 0) {
          #pragma unroll
          for (int e = 0; e < 8; ++e) {
            unsigned short hh, ll;
            f2hl(sv[32 * kc + 8 * g + e], hh, ll);
            vh[e] = (short)hh; vl[e] = (short)ll;
          }
        }
        MFMA2L(accBv, btf_h[kc], vh, vl)
      }
      #pragma unroll
      for (int rg = 0; rg < 4; ++rg) sVuu[(4 * g + rg) * 17 + r] = accU[rg];
      if (r == 0) {
        #pragma unroll
        for (int rg = 0; rg < 4; ++rg) sBtv[4 * g + rg] = accBv[rg];
      }
    } else {
      const int nc = (wv == 1) ? 2 : 1;
      #pragma unroll
      for (int ci = 0; ci < 2; ++ci) {
        if (ci < nc) {
          const int c = (wv == 1) ? (ci == 0 ? 0 : 3) : (wv - 1);
          f32x4 acc = {};
          #pragma unroll
          for (int kc = 0; kc < 2; ++kc) {
            bf16x8 yh = ld64(sWth, 16 * c + r, 4 * kc + g);
            bf16x8 yl = ld64(sWtl, 16 * c + r, 4 * kc + g);
            MFMA2L(acc, btf_h[kc], yh, yl)
          }
          u16x4 h4, l4; cvt4(acc, h4, l4);
          st16s(sBWh, 16 * c + r, 4 * g, h4);
          st16s(sBWl, 16 * c + r, 4 * g, l4);
        }
      }
    }
    if (t > 0) ATW(0);
    __syncthreads();

    // ===== P_C: chol+M (w0) | ATW(1)+Atv (w1,w2) | ATW(1) (w3) =====
    if (wv == 0) {
      const int u = r;
      float rr[16];
      #pragma unroll
      for (int k = 0; k < 16; ++k) rr[k] = sVuu[u * 17 + k];
      #pragma unroll
      for (int j = 0; j < 16; ++j) {
        float s = rr[j];
        #pragma unroll
        for (int k = 0; k < j; ++k) s -= rr[k] * __shfl(rr[k], j);
        const float dj  = sqrtf(__shfl(s, j));
        const float inv = 1.f / dj;
        rr[j] = (u == j) ? dj : s * inv;
      }
      float idia[16];
      #pragma unroll
      for (int i = 0; i < 16; ++i) idia[i] = 1.f / __shfl(rr[i], i);
      float x[16];
      #pragma unroll
      for (int i = 0; i < 16; ++i) {
        float s = (i == u) ? 1.f : 0.f;
        #pragma unroll
        for (int k = 0; k < i; ++k) s -= __shfl(rr[k], i) * x[k];
        x[i] = s * idia[i];
      }
      if (lane < 16) {   // lane u holds column u of M: x[i] = M[i][u]
        #pragma unroll
        for (int i = 0; i < 16; ++i) {
          sMT[u * 17 + i] = x[i];
          unsigned short hh, ll;
          f2hl(x[i], hh, ll);
          sMth[u * 16 + i] = hh; sMtl[u * 16 + i] = ll;  // Mt[u][i]=M[i][u]
          sMbh[i * 16 + u] = hh; sMbl[i * 16 + u] = ll;  // Mb[i][u]=M[i][u]
        }
      }
    } else if (wv <= 2) {
      if (t > 0) {
        ATW(1);
        const int rb = 2 * (wv - 1);
        f32x4 at0 = {}, at1 = {};
        #pragma unroll
        for (int kc = 0; kc < 2; ++kc) {
          int kcg = 4 * kc + g;
          bf16x8 vh = {}, vl = {};
          if (r == 0) {
            #pragma unroll
            for (int e = 0; e < 8; ++e) {
              unsigned short hh, ll;
              f2hl(sv[32 * kc + 8 * g + e], hh, ll);
              vh[e] = (short)hh; vl[e] = (short)ll;
            }
          }
          bf16x8 xh = ld64(sAth, 16 * rb + r, kcg);
          MFMA2L(at0, xh, vh, vl)
          xh = ld64(sAth, 16 * (rb + 1) + r, kcg);
          MFMA2L(at1, xh, vh, vl)
        }
        if (r == 0) {
          #pragma unroll
          for (int rg = 0; rg < 4; ++rg) {
            sVp[16 * rb + 4 * g + rg]       = at0[rg];
            sVp[16 * (rb + 1) + 4 * g + rg] = at1[rg];
          }
        }
      }
    } else {
      if (t > 0) ATW(1);
    }
    __syncthreads();

    // ===== P_D: S=M*BtW (in-place) + Kg=Mt*S -> gOut (w1,w2) | kg (w3) | ATW(1) (w0) =====
    if (wv == 0) {
      if (t > 0) ATW(1);
    } else if (wv <= 2) {
      const int cb = 2 * (wv - 1);
      #pragma unroll
      for (int ci = 0; ci < 2; ++ci) {
        const int c = cb + ci;
        f32x4 sacc = {};
        {
          bf16x8 xh = ld16s(sMbh, r, g), xl = ld16s(sMbl, r, g);
          bf16x8 yh = ld16s(sBWh, 16 * c + r, g), yl = ld16s(sBWl, 16 * c + r, g);
          MFMA3(sacc, xh, xl, yh, yl)       // D[u][j] = S[u][j]
        }
        u16x4 h4, l4; cvt4(sacc, h4, l4);
        st16s(sBWh, 16 * c + r, 4 * g, h4); // St[j][u] = S[u][j], overwrites BtW
        st16s(sBWl, 16 * c + r, 4 * g, l4);
        f32x4 kacc = {};
        {
          bf16x8 xh = ld16s(sMth, r, g), xl = ld16s(sMtl, r, g);
          bf16x8 yh = ld16s(sBWh, 16 * c + r, g), yl = ld16s(sBWl, 16 * c + r, g);
          MFMA3(kacc, xh, xl, yh, yl)       // D[u][j] = Kg[u][j]
        }
        #pragma unroll
        for (int rg = 0; rg < 4; ++rg)
          gOut[obase + (size_t)(4 * g + rg) * 65 + 16 * c + r] = kacc[rg];
      }
    } else {
      if (lane < 16) {
        wt_ = 0.f;
        #pragma unroll
        for (int u2 = 0; u2 < 16; ++u2)
          wt_ += sMT[u2 * 17 + lane] * sBtv[u2];   // w~ = M * Btv
        float kgv = 0.f;
        #pragma unroll
        for (int w2 = 0; w2 < 16; ++w2)
          kgv += __shfl(wt_, w2) * sMT[lane * 17 + w2];  // kg = M^T w~
        gOut[obase + (size_t)lane * 65 + 64] = kgv;
      }
    }
    __syncthreads();

    // ===== P_E: Vnew = Q + A^T W - S^T S -> sV ; v update (w3) =====
    if (t > 0) {
      bf16x8 xnh = negbf(ld16s(sBWh, 16 * it + r, g));
      bf16x8 xnl = negbf(ld16s(sBWl, 16 * it + r, g));
      u16x4 h4, l4;
      #pragma unroll
      for (int c = 0; c < 4; ++c) {
        bf16x8 yh = ld16s(sBWh, 16 * c + r, g);
        bf16x8 yl = ld16s(sBWl, 16 * c + r, g);
        MFMA3(vacc[c], xnh, xnl, yh, yl)
        cvt4(vacc[c], h4, l4);
        st64_4(sVh, 16 * c + r, 16 * it + 4 * g, h4);
        st64_4(sVl, 16 * c + r, 16 * it + 4 * g, l4);
      }
      if (wv == 3) {
        const int i = lane;
        float s = qgt + sVp[i];
        #pragma unroll
        for (int u2 = 0; u2 < 16; ++u2)
          s -= rec(sBWh[i * 16 + u2], sBWl[i * 16 + u2]) * __shfl(wt_, u2);
        sv[i] = s;   // v_new = qg + A^T v - S^T w~
      }
    }
    __syncthreads();
  }
}

extern "C" void kernel_launch(void* const* d_in, const int* in_sizes, int n_in,
                              void* d_out, int out_size, void* d_ws, size_t ws_size,
                              hipStream_t stream) {
  (void)n_in; (void)out_size; (void)d_ws; (void)ws_size;
  const float* A = (const float*)d_in[0];
  const float* B = (const float*)d_in[1];
  const float* Q = (const float*)d_in[2];
  const float* R = (const float*)d_in[3];
  const float* G = (const float*)d_in[4];
  float* out = (float*)d_out;
  const int bsz = in_sizes[3] / 256;   // R is bsz*16*16
  lqr5<<<bsz, NT, 0, stream>>>(A, B, Q, R, G, out, bsz);
}